// Round 2
// baseline (321.213 us; speedup 1.0000x reference)
//
#include <hip/hip_runtime.h>
#include <float.h>

#define BB 256
#define DD 256
#define KK 1024
#define EE 16
#define DECAY 0.999f
#define GAIN  0.001f
#define EPS   1e-6f

// output offsets in floats (tuple order: cw_embed, one_hot, new_codebook, new_ema)
#define OH_OFF   ((size_t)BB * DD * EE)                    // 1048576
#define CB_OFF   (OH_OFF + (size_t)BB * DD * KK)           // 68157440
#define EMA_OFF  (CB_OFF + (size_t)DD * KK * EE)           // 72351744

typedef float f32x4 __attribute__((ext_vector_type(4)));

__device__ __forceinline__ float dot16(const float4& a0, const float4& a1,
                                       const float4& a2, const float4& a3,
                                       const float4& b0, const float4& b1,
                                       const float4& b2, const float4& b3) {
  float s = a0.x * b0.x;
  s = fmaf(a0.y, b0.y, s); s = fmaf(a0.z, b0.z, s); s = fmaf(a0.w, b0.w, s);
  s = fmaf(a1.x, b1.x, s); s = fmaf(a1.y, b1.y, s); s = fmaf(a1.z, b1.z, s); s = fmaf(a1.w, b1.w, s);
  s = fmaf(a2.x, b2.x, s); s = fmaf(a2.y, b2.y, s); s = fmaf(a2.z, b2.z, s); s = fmaf(a2.w, b2.w, s);
  s = fmaf(a3.x, b3.x, s); s = fmaf(a3.y, b3.y, s); s = fmaf(a3.z, b3.z, s); s = fmaf(a3.w, b3.w, s);
  return s;
}

// monotonic ordered-uint of an f32; key = ord<<32 | k. atomicMin -> smallest
// dist, lowest k on exact ties (identical to strict-< ascending-k scan).
__device__ __forceinline__ unsigned long long packkey(float dist, int k) {
  unsigned u = __float_as_uint(dist);
  unsigned m = ((int)u < 0) ? 0xFFFFFFFFu : 0x80000000u;
  return ((unsigned long long)(u ^ m) << 32) | (unsigned long long)(unsigned)k;
}

__device__ __forceinline__ void ntst4(float4* p, float4 v) {
  f32x4 t = { v.x, v.y, v.z, v.w };
  __builtin_nontemporal_store(t, (f32x4*)p);
}

// One block per d. 1024 threads = 16 waves, WAVE-SPECIALIZED in P1:
//   waves 0-7 : compute — scan k in [128w, 128w+128), 4 b's/lane, NO stores
//   waves 8-15: streamer — each pushes 32 one_hot rows (128 KB) of zeros as a
//               pure NT-store stream (no VALU/LDS work, BW-paced)
// This removes the intra-wave store<->LDS/VALU serialization that made the
// interleaved variants (R0/R1) insensitive to occupancy.
// Argmin merged via packed-u64 LDS atomicMin. LDS ~143 KB -> 1 block/CU.
__global__ __launch_bounds__(1024) void vqvae_fused(
    const float* __restrict__ cw_q,      // (B, D*E)
    const float* __restrict__ codebook,  // (D, K, E)
    const float* __restrict__ ema,       // (D, K)
    float* __restrict__ out)
{
  __shared__ float4 cb4s[KK * EE / 4];            // 64 KB codebook row d
  __shared__ float4 upd4s[KK * EE / 4];           // 64 KB update accumulator
  __shared__ float  c2s[KK];                      // 4 KB |c|^2
  __shared__ float  esh[KK];                      // 4 KB old ema (prefetched)
  __shared__ float  cnts[KK];                     // 4 KB
  __shared__ unsigned long long amin[BB];         // 2 KB packed argmin
  __shared__ int    ish[BB];                      // 1 KB

  const int t = threadIdx.x;
  const int d = blockIdx.x;
  const int w = t >> 6;
  const int l = t & 63;
  const float4 z4 = make_float4(0.f, 0.f, 0.f, 0.f);

  // ---- P0: init LDS, prefetch ema, stage codebook, load x fragments ----
  cnts[t] = 0.f;
  if (t < BB) amin[t] = ~0ULL;
  esh[t] = ema[(size_t)d * KK + t];
  #pragma unroll
  for (int i = 0; i < 4; ++i) upd4s[i * 1024 + t] = z4;

  const float4* src4 = (const float4*)codebook + (size_t)d * (KK * EE / 4);
  #pragma unroll
  for (int i = 0; i < 4; ++i) {
    int i4 = i * 1024 + t;
    float4 v = src4[i4];
    cb4s[i4] = v;
    float sq = v.x * v.x;
    sq = fmaf(v.y, v.y, sq);
    sq = fmaf(v.z, v.z, sq);
    sq = fmaf(v.w, v.w, sq);
    sq += __shfl_xor(sq, 1);
    sq += __shfl_xor(sq, 2);
    if ((t & 3) == 0) c2s[i4 >> 2] = sq;
  }

  float4 xv[4][4];
  float  x2[4];
  if (w < 8) {   // compute waves own the x fragments (4 b's per lane)
    #pragma unroll
    for (int j = 0; j < 4; ++j) {
      const int b = l + 64 * j;
      const float4* xr = (const float4*)cw_q + (size_t)b * (DD * EE / 4) + d * 4;
      xv[j][0] = xr[0]; xv[j][1] = xr[1]; xv[j][2] = xr[2]; xv[j][3] = xr[3];
    }
    #pragma unroll
    for (int j = 0; j < 4; ++j)
      x2[j] = dot16(xv[j][0], xv[j][1], xv[j][2], xv[j][3],
                    xv[j][0], xv[j][1], xv[j][2], xv[j][3]);
  }

  __syncthreads();

  // ---- P1: specialized — compute scan (w<8)  ||  one_hot zero stream (w>=8) ----
  float* ohp = out + OH_OFF;

  float best[4] = {FLT_MAX, FLT_MAX, FLT_MAX, FLT_MAX};
  int   bi[4]   = {0, 0, 0, 0};

  if (w < 8) {
    const int kbase = w << 7;    // 128 k's per compute wave
    #pragma unroll 2
    for (int s = 0; s < 128; ++s) {
      const int k = kbase + s;
      const float4* p = cb4s + (k << 2);     // wave-uniform -> LDS broadcast
      float4 c0 = p[0], c1 = p[1], c2v = p[2], c3 = p[3];
      const float c2k = c2s[k];
      #pragma unroll
      for (int j = 0; j < 4; ++j) {
        float dj = dot16(c0, c1, c2v, c3, xv[j][0], xv[j][1], xv[j][2], xv[j][3]);
        float dist = fmaf(-2.f, dj, x2[j] + c2k);
        if (dist < best[j]) { best[j] = dist; bi[j] = k; }   // strict <: lowest k wins
      }
    }
    // flush per-thread argmin into packed atomicMin (replaces merge phase)
    #pragma unroll
    for (int j = 0; j < 4; ++j)
      atomicMin(&amin[l + 64 * j], packkey(best[j], bi[j]));
  } else {
    // streamer wave sw owns one_hot rows b in [32*sw, 32*sw+32) for column d
    const int sw = w - 8;
    #pragma unroll 1
    for (int r = 0; r < 32; ++r) {
      const int b = (sw << 5) + r;
      float4* zb = (float4*)(ohp + (size_t)b * (DD * KK) + (size_t)d * KK) + l;
      ntst4(&zb[0],   z4);
      ntst4(&zb[64],  z4);
      ntst4(&zb[128], z4);
      ntst4(&zb[192], z4);
    }
  }

  __syncthreads();   // drains streamer vmcnt + compute-wave amin atomics

  // ---- P2: epilogue per b + prefetch scatter operands (addresses static) ----
  const int e = t & 15;
  const int g = t >> 4;                    // 64 groups handle 4 b's each
  float xpre[4];
  #pragma unroll
  for (int i = 0; i < 4; ++i)
    xpre[i] = cw_q[(size_t)(g * 4 + i) * (DD * EE) + (size_t)d * EE + e];

  if (t < BB) {
    const int b = t;
    unsigned long long key = amin[b];
    const int bidx = (int)(unsigned)(key & 0xFFFFFFFFull);

    float4* ce = (float4*)out + (size_t)b * (DD * EE / 4) + d * 4;
    const float4* cwp = cb4s + (bidx << 2);
    ntst4(&ce[0], cwp[0]); ntst4(&ce[1], cwp[1]);
    ntst4(&ce[2], cwp[2]); ntst4(&ce[3], cwp[3]);

    __builtin_nontemporal_store(
        1.0f, &ohp[(size_t)b * (DD * KK) + (size_t)d * KK + bidx]);

    ish[b] = bidx;
    atomicAdd(&cnts[bidx], 1.0f);
  }
  __syncthreads();

  // ---- P3+P4 merged: update scatter (e-split banks) + new_ema ----
  {
    float* upd = (float*)upd4s;
    #pragma unroll
    for (int i = 0; i < 4; ++i) {
      int k = ish[g * 4 + i];
      atomicAdd(&upd[k * EE + e], xpre[i]);
    }
    float* oe = out + EMA_OFF + (size_t)d * KK;
    __builtin_nontemporal_store(DECAY * esh[t] + GAIN * cnts[t], &oe[t]);
  }
  __syncthreads();

  // ---- P5: new_codebook ----
  {
    float4* ocb = (float4*)(out + CB_OFF) + (size_t)d * (KK * EE / 4);
    #pragma unroll
    for (int i = 0; i < 4; ++i) {
      int i4 = i * 1024 + t;
      int k  = i4 >> 2;
      float4 c = cb4s[i4];
      float4 u = upd4s[i4];
      float inv = GAIN / (esh[k] + EPS);
      float4 r;
      r.x = DECAY * c.x + u.x * inv;
      r.y = DECAY * c.y + u.y * inv;
      r.z = DECAY * c.z + u.z * inv;
      r.w = DECAY * c.w + u.w * inv;
      ntst4(&ocb[i4], r);
    }
  }
}

extern "C" void kernel_launch(void* const* d_in, const int* in_sizes, int n_in,
                              void* d_out, int out_size, void* d_ws, size_t ws_size,
                              hipStream_t stream) {
  const float* cw_q     = (const float*)d_in[0];
  const float* codebook = (const float*)d_in[1];
  const float* ema      = (const float*)d_in[2];
  float* out = (float*)d_out;
  (void)in_sizes; (void)n_in; (void)out_size; (void)d_ws; (void)ws_size;

  vqvae_fused<<<dim3(DD), dim3(1024), 0, stream>>>(cw_q, codebook, ema, out);
}